// Round 5
// baseline (4745.769 us; speedup 1.0000x reference)
//
#include <hip/hip_runtime.h>
#include <math.h>

// ChamferLoss on MI355X — round 5: two-pass LDS-broadcast NN.
// Round 1/4 post-mortem: ring-shuffle register blocking was starved by the
// allocator (VGPR_Count 56-72 vs ~100+ live values) -> AGPR spill/fill VALU
// traffic ~2x instruction bloat. This round: canonical pattern. Each thread
// owns RI=8 rows in registers; columns staged in LDS and broadcast-read;
// per-direction min chains are thread-private. Two directions = blockIdx.y.
// d(p,q) = 2*(hp + hq - p.q); row chain keeps min_j (hq_j - t).

#define N_PTS 147456     // 384*384
#define IMG_W 384
#define RI 8             // rows per thread
#define ROWS_BLK 2048    // 256 threads * RI
#define NRBLK 72         // N_PTS / ROWS_BLK
#define SB 32            // column slices (parallelism + atomic partials)
#define COLS_SLICE 4608  // N_PTS / SB
#define TC 512           // columns staged in LDS per stage (8 KB)

__device__ __forceinline__ float min3f(float a, float b, float c) {
    float r;
    asm("v_min3_f32 %0, %1, %2, %3" : "=v"(r) : "v"(a), "v"(b), "v"(c));
    return r;
}

// monotonic float->uint map: uint order == float order (handles negatives)
__device__ __forceinline__ unsigned encf(float f) {
    unsigned u = __float_as_uint(f);
    return (u & 0x80000000u) ? ~u : (u | 0x80000000u);
}
__device__ __forceinline__ float decf(unsigned k) {
    return __uint_as_float((k & 0x80000000u) ? (k ^ 0x80000000u) : ~k);
}

// depth -> (x,y,z, 0.5*|xyz|^2) for both clouds; init min buffers.
__global__ __launch_bounds__(256) void prep_kernel(
    const float* __restrict__ fake, const float* __restrict__ tar,
    const int* __restrict__ sh_p, const int* __restrict__ sw_p,
    float4* __restrict__ A, float4* __restrict__ B,
    unsigned* __restrict__ minbuf)
{
    int idx = blockIdx.x * 256 + threadIdx.x;
    if (idx >= N_PTS) return;
    int r = idx / IMG_W, c = idx - r * IMG_W;
    int sh = *sh_p, sw = *sw_p;
    float cw = (float)((double)sw / 1285.0 * 360.0);
    float ch = (float)((double)sh / 438.0 * 123.5);
    const float fh = (float)(360.0 * 384.0 / 1285.0);   // fh_crop
    const float fv = (float)(123.5 * 384.0 / 438.0);    // fv_crop
    const float D2R = 0.017453292519943295f;
    float yaw = ((-fh * (float)c) / 384.0f + cw) * D2R;
    float pit = ((-fv * (float)r) / 384.0f + ch) * D2R;
    float sy = sinf(yaw), cy = cosf(yaw);
    float sp = sinf(pit), cp = cosf(pit);
    float dt = tar[idx], df = fake[idx];
    float px = dt * sy * sp, py = dt * cy * sp, pz = dt * cp;
    float qx = df * sy * sp, qy = df * cy * sp, qz = df * cp;
    A[idx] = make_float4(px, py, pz, 0.5f * (px * px + py * py + pz * pz));
    B[idx] = make_float4(qx, qy, qz, 0.5f * (qx * qx + qy * qy + qz * qz));
    minbuf[idx]         = 0xFFFFFFFFu;   // encodes +inf
    minbuf[idx + N_PTS] = 0xFFFFFFFFu;
}

// One direction per blockIdx.y: y=0 rows=A cols=B -> rowmin; y=1 swapped.
// blockIdx.x = rblk*SB + slice. Each thread: 8 rows in regs, min over the
// slice's 4608 cols staged through LDS in 9 stages of 512.
__global__ __launch_bounds__(256) void nn_pass(
    const float4* __restrict__ A, const float4* __restrict__ B,
    unsigned* __restrict__ rowmin, unsigned* __restrict__ colmin)
{
    __shared__ float4 tile[TC];
    const int tid = threadIdx.x;
    const int dir = blockIdx.y;
    const float4* __restrict__ R = dir ? B : A;
    const float4* __restrict__ C = dir ? A : B;
    unsigned* __restrict__ outm  = dir ? colmin : rowmin;

    const int rblk  = blockIdx.x / SB;
    const int slice = blockIdx.x - rblk * SB;
    const int rbase = rblk * ROWS_BLK;
    const int cbase0 = slice * COLS_SLICE;

    float ax[RI], ay[RI], az[RI], racc[RI];
    #pragma unroll
    for (int k = 0; k < RI; k++) {
        float4 p = R[rbase + k * 256 + tid];   // coalesced
        ax[k] = p.x; ay[k] = p.y; az[k] = p.z;
        racc[k] = __builtin_inff();
    }

    #pragma unroll 1
    for (int stage = 0; stage < COLS_SLICE / TC; stage++) {
        const int cbase = cbase0 + stage * TC;
        #pragma unroll
        for (int i = 0; i < TC / 256; i++)
            tile[i * 256 + tid] = C[cbase + i * 256 + tid];
        __syncthreads();

        #pragma unroll 2
        for (int j = 0; j < TC; j += 4) {
            float4 q0 = tile[j], q1 = tile[j + 1];   // broadcast ds_read_b128
            float4 q2 = tile[j + 2], q3 = tile[j + 3];
            #pragma unroll
            for (int k = 0; k < RI; k++) {
                float t0 = ax[k] * q0.x + ay[k] * q0.y + az[k] * q0.z;
                float t1 = ax[k] * q1.x + ay[k] * q1.y + az[k] * q1.z;
                float t2 = ax[k] * q2.x + ay[k] * q2.y + az[k] * q2.z;
                float t3 = ax[k] * q3.x + ay[k] * q3.y + az[k] * q3.z;
                racc[k] = min3f(racc[k], q0.w - t0, q1.w - t1);
                racc[k] = min3f(racc[k], q2.w - t2, q3.w - t3);
            }
        }
        __syncthreads();
    }

    #pragma unroll
    for (int k = 0; k < RI; k++)
        atomicMin(&outm[rbase + k * 256 + tid], encf(racc[k]));
}

// sum over i of (hp_i + rowdec_i) + (hq_i + coldec_i), per-block partials
__global__ __launch_bounds__(256) void reduce1(
    const float4* __restrict__ A, const float4* __restrict__ B,
    const unsigned* __restrict__ rowmin, const unsigned* __restrict__ colmin,
    float* __restrict__ partials)
{
    int tid = threadIdx.x;
    int base = blockIdx.x * 1024;
    float s = 0.f;
    #pragma unroll
    for (int t = 0; t < 4; t++) {
        int i = base + t * 256 + tid;
        s += A[i].w + decf(rowmin[i]);
        s += B[i].w + decf(colmin[i]);
    }
    #pragma unroll
    for (int off = 32; off; off >>= 1) s += __shfl_xor(s, off, 64);
    __shared__ float wsum[4];
    if ((tid & 63) == 0) wsum[tid >> 6] = s;
    __syncthreads();
    if (tid == 0) partials[blockIdx.x] = wsum[0] + wsum[1] + wsum[2] + wsum[3];
}

__global__ __launch_bounds__(256) void reduce2(
    const float* __restrict__ partials, float* __restrict__ out)
{
    int tid = threadIdx.x;
    float s = 0.f;
    for (int i = tid; i < 144; i += 256) s += partials[i];
    #pragma unroll
    for (int off = 32; off; off >>= 1) s += __shfl_xor(s, off, 64);
    __shared__ float wsum[4];
    if ((tid & 63) == 0) wsum[tid >> 6] = s;
    __syncthreads();
    if (tid == 0) out[0] = 2.0f * (wsum[0] + wsum[1] + wsum[2] + wsum[3]) / 147456.0f;
}

extern "C" void kernel_launch(void* const* d_in, const int* in_sizes, int n_in,
                              void* d_out, int out_size, void* d_ws, size_t ws_size,
                              hipStream_t stream) {
    const float* fake = (const float*)d_in[0];
    const float* tar  = (const float*)d_in[1];
    const int*   sh_p = (const int*)d_in[2];
    const int*   sw_p = (const int*)d_in[3];
    float* out = (float*)d_out;

    char* ws = (char*)d_ws;
    float4*   A      = (float4*)ws;                                   // P (tar)  [N]
    float4*   Bc     = (float4*)(ws + (size_t)N_PTS * 16);            // Q (fake) [N]
    unsigned* minbuf = (unsigned*)(ws + (size_t)2 * N_PTS * 16);      // rowmin|colmin [2N]
    float*    parts  = (float*)(ws + (size_t)2 * N_PTS * 16 + (size_t)2 * N_PTS * 4);

    prep_kernel<<<(N_PTS + 255) / 256, 256, 0, stream>>>(fake, tar, sh_p, sw_p, A, Bc, minbuf);
    dim3 grid(NRBLK * SB, 2);
    nn_pass<<<grid, 256, 0, stream>>>(A, Bc, minbuf, minbuf + N_PTS);
    reduce1<<<N_PTS / 1024, 256, 0, stream>>>(A, Bc, minbuf, minbuf + N_PTS, parts);
    reduce2<<<1, 256, 0, stream>>>(parts, out);
}

// Round 7
// 1996.036 us; speedup vs baseline: 2.3776x; 2.3776x over previous
//
#include <hip/hip_runtime.h>
#include <math.h>

// ChamferLoss on MI355X — round 7: grid-accelerated exact NN, workspace-safe.
// Round 6 crashed (device abort). Diagnosis: ws overflow — needed 8.56 MB vs
// only ~5.9 MB proven available. This round fits in 5.35 MB:
//   - counts/offsets/cursor share ONE buffer (in-place scan, in-place fill;
//     after fill, offc[c] = END of cell c; start = c ? offc[c-1] : 0)
//   - query result stored in the point's own float4.w (readers only use xyz)
//   - no hipMemsetAsync (zero kernel instead)
// Algorithm unchanged: 48^3 grid over [-50,50]^3, CSR binning, expanding-
// shell exact NN with conservative termination bound (~1e8 candidate evals
// vs 2.17e10 brute force; brute-force VALU ceiling measured at ~3.3 ms).

#define N_PTS 147456          // 384*384
#define N2    (2 * N_PTS)     // both clouds
#define IMG_W 384
#define G     48              // grid edge
#define NC    (G * G * G)     // 110592 cells per cloud
#define NCI   (2 * NC)        // 221184 cells total
#define SCALE 0.48f           // cells per meter: (x+50)*SCALE in [0,48)
#define HC    2.0833333f      // cell width lower bound (conservative)
#define SCAN_BLOCKS 864       // NCI / 256

// ---- shared geometry (count & fill & query must agree exactly) ----

__device__ __forceinline__ float4 transform_pt(
    int idx, const float* __restrict__ fake, const float* __restrict__ tar,
    int sh, int sw)
{
    int pix = (idx < N_PTS) ? idx : idx - N_PTS;
    int r = pix / IMG_W, c = pix - r * IMG_W;
    float cw = (float)((double)sw / 1285.0 * 360.0);
    float ch = (float)((double)sh / 438.0 * 123.5);
    const float fh = (float)(360.0 * 384.0 / 1285.0);   // fh_crop
    const float fv = (float)(123.5 * 384.0 / 438.0);    // fv_crop
    const float D2R = 0.017453292519943295f;
    float yaw = ((-fh * (float)c) / 384.0f + cw) * D2R;
    float pit = ((-fv * (float)r) / 384.0f + ch) * D2R;
    float sy = sinf(yaw), cy = cosf(yaw);
    float sp = sinf(pit), cp = cosf(pit);
    float d = (idx < N_PTS) ? tar[pix] : fake[pix];   // A=transform(tar), B=transform(fake)
    return make_float4(d * sy * sp, d * cy * sp, d * cp, 0.f);
}

__device__ __forceinline__ int cell_coord(float v) {
    int c = (int)((v + 50.0f) * SCALE);
    return min(max(c, 0), G - 1);
}

__device__ __forceinline__ int cell_of(float x, float y, float z) {
    return (cell_coord(z) * G + cell_coord(y)) * G + cell_coord(x);
}

// ---- pipeline ----

__global__ __launch_bounds__(256) void zero_kernel(int* __restrict__ p) {
    p[blockIdx.x * 256 + threadIdx.x] = 0;   // grid = SCAN_BLOCKS covers NCI
}

// 1) histogram points into [cellsA | cellsB] (offc doubles as counts)
__global__ __launch_bounds__(256) void count_kernel(
    const float* __restrict__ fake, const float* __restrict__ tar,
    const int* __restrict__ sh_p, const int* __restrict__ sw_p,
    int* __restrict__ offc)
{
    int idx = blockIdx.x * 256 + threadIdx.x;    // grid = N2/256
    float4 p = transform_pt(idx, fake, tar, *sh_p, *sw_p);
    int bucket = ((idx < N_PTS) ? 0 : NC) + cell_of(p.x, p.y, p.z);
    atomicAdd(&offc[bucket], 1);
}

// 2) per-block exclusive scan IN PLACE; block sums -> bsum
__global__ __launch_bounds__(256) void scan1_kernel(
    int* __restrict__ offc, int* __restrict__ bsum)
{
    __shared__ int sd[256];
    int t = threadIdx.x;
    int gid = blockIdx.x * 256 + t;
    int c = offc[gid];
    sd[t] = c;
    __syncthreads();
    for (int o = 1; o < 256; o <<= 1) {
        int v = (t >= o) ? sd[t - o] : 0;
        __syncthreads();
        sd[t] += v;
        __syncthreads();
    }
    offc[gid] = sd[t] - c;                        // exclusive within block
    if (t == 255) bsum[blockIdx.x] = sd[255];
}

// 3) exclusive scan of the 864 block sums (in place)
__global__ __launch_bounds__(1024) void scan2_kernel(int* __restrict__ bsum)
{
    __shared__ int sd[1024];
    int t = threadIdx.x;
    int v0 = (t < SCAN_BLOCKS) ? bsum[t] : 0;
    sd[t] = v0;
    __syncthreads();
    for (int o = 1; o < 1024; o <<= 1) {
        int v = (t >= o) ? sd[t - o] : 0;
        __syncthreads();
        sd[t] += v;
        __syncthreads();
    }
    if (t < SCAN_BLOCKS) bsum[t] = sd[t] - v0;    // exclusive
}

// 4) add block offsets in place -> global exclusive offsets (= fill cursor)
__global__ __launch_bounds__(256) void scan3_kernel(
    int* __restrict__ offc, const int* __restrict__ bsum)
{
    int gid = blockIdx.x * 256 + threadIdx.x;
    offc[gid] += bsum[blockIdx.x];
}

// 5) scatter points into CSR slots (cursor = offc, consumed in place).
//    After this kernel offc[c] = END offset of cell c.
__global__ __launch_bounds__(256) void fill_kernel(
    const float* __restrict__ fake, const float* __restrict__ tar,
    const int* __restrict__ sh_p, const int* __restrict__ sw_p,
    int* __restrict__ offc, float4* __restrict__ pts)
{
    int idx = blockIdx.x * 256 + threadIdx.x;
    float4 p = transform_pt(idx, fake, tar, *sh_p, *sw_p);
    int bucket = ((idx < N_PTS) ? 0 : NC) + cell_of(p.x, p.y, p.z);
    int slot = atomicAdd(&offc[bucket], 1);
    pts[slot] = make_float4(p.x, p.y, p.z, 0.f);
}

// 6) expanding-shell exact NN; writes best into own pts[tid].w.
//    CSR range of cells [c0..c1]: [ c0 ? offc[c0-1] : 0 , offc[c1] ).
__global__ __launch_bounds__(256) void query_kernel(
    float4* __restrict__ pts, const int* __restrict__ offc)
{
    int tid = blockIdx.x * 256 + threadIdx.x;
    float4 q = pts[tid];
    float qx = q.x, qy = q.y, qz = q.z;
    int base = (tid < N_PTS) ? NC : 0;            // search the OTHER grid

    int cx = cell_coord(qx), cy = cell_coord(qy), cz = cell_coord(qz);
    float fx = (qx + 50.0f) * SCALE - (float)cx;
    float fy = (qy + 50.0f) * SCALE - (float)cy;
    float fz = (qz + 50.0f) * SCALE - (float)cz;
    float m = fminf(fminf(fminf(fx, 1.0f - fx), fminf(fy, 1.0f - fy)),
                    fminf(fz, 1.0f - fz));
    m = fmaxf(m, 0.0f);

    float best = __builtin_inff();

    for (int s = 0; s <= G; ++s) {
        int zlo = max(cz - s, 0), zhi = min(cz + s, G - 1);
        for (int iz = zlo; iz <= zhi; ++iz) {
            int adz = iz - cz; adz = (adz < 0) ? -adz : adz;
            int ylo = max(cy - s, 0), yhi = min(cy + s, G - 1);
            for (int iy = ylo; iy <= yhi; ++iy) {
                int ady = iy - cy; ady = (ady < 0) ? -ady : ady;
                int rowb = base + (iz * G + iy) * G;
                if (adz == s || ady == s) {        // full row of the shell
                    int c0 = rowb + max(cx - s, 0);
                    int c1 = rowb + min(cx + s, G - 1);
                    int lo = c0 ? offc[c0 - 1] : 0;
                    int hi = offc[c1];
                    for (int j = lo; j < hi; ++j) {
                        float4 t = pts[j];
                        float dx = t.x - qx, dy = t.y - qy, dz = t.z - qz;
                        float d = fmaf(dx, dx, fmaf(dy, dy, dz * dz));
                        best = fminf(best, d);
                    }
                } else {                            // interior row: two end cells
                    if (cx - s >= 0) {
                        int c0 = rowb + cx - s;
                        int lo = c0 ? offc[c0 - 1] : 0;
                        int hi = offc[c0];
                        for (int j = lo; j < hi; ++j) {
                            float4 t = pts[j];
                            float dx = t.x - qx, dy = t.y - qy, dz = t.z - qz;
                            float d = fmaf(dx, dx, fmaf(dy, dy, dz * dz));
                            best = fminf(best, d);
                        }
                    }
                    if (cx + s <= G - 1) {
                        int c0 = rowb + cx + s;
                        int lo = c0 ? offc[c0 - 1] : 0;
                        int hi = offc[c0];
                        for (int j = lo; j < hi; ++j) {
                            float4 t = pts[j];
                            float dx = t.x - qx, dy = t.y - qy, dz = t.z - qz;
                            float d = fmaf(dx, dx, fmaf(dy, dy, dz * dz));
                            best = fminf(best, d);
                        }
                    }
                }
            }
        }
        // all unscanned points are >= (s + m) cell-widths away (conservative)
        float bnd = ((float)s + m) * HC;
        if (best <= bnd * bnd) break;
    }

    pts[tid].w = best;   // only this thread's w lane; readers consume xyz only
}

// 7) deterministic sum of pts[*].w
__global__ __launch_bounds__(256) void reduce1(
    const float4* __restrict__ pts, float* __restrict__ partials)
{
    int tid = threadIdx.x;
    int basei = blockIdx.x * 1024;
    float s = 0.f;
    #pragma unroll
    for (int t = 0; t < 4; t++) s += pts[basei + t * 256 + tid].w;
    #pragma unroll
    for (int o = 32; o; o >>= 1) s += __shfl_xor(s, o, 64);
    __shared__ float wsum[4];
    if ((tid & 63) == 0) wsum[tid >> 6] = s;
    __syncthreads();
    if (tid == 0) partials[blockIdx.x] = wsum[0] + wsum[1] + wsum[2] + wsum[3];
}

__global__ __launch_bounds__(256) void reduce2(
    const float* __restrict__ partials, float* __restrict__ out)
{
    int tid = threadIdx.x;
    float s = 0.f;
    for (int i = tid; i < 288; i += 256) s += partials[i];
    #pragma unroll
    for (int o = 32; o; o >>= 1) s += __shfl_xor(s, o, 64);
    __shared__ float wsum[4];
    if ((tid & 63) == 0) wsum[tid >> 6] = s;
    __syncthreads();
    if (tid == 0) out[0] = (wsum[0] + wsum[1] + wsum[2] + wsum[3]) / 147456.0f;
}

extern "C" void kernel_launch(void* const* d_in, const int* in_sizes, int n_in,
                              void* d_out, int out_size, void* d_ws, size_t ws_size,
                              hipStream_t stream) {
    const float* fake = (const float*)d_in[0];
    const float* tar  = (const float*)d_in[1];
    const int*   sh_p = (const int*)d_in[2];
    const int*   sw_p = (const int*)d_in[3];
    float* out = (float*)d_out;

    // ws layout: total 5,608,576 B = 5.35 MB (< 5.90 MB proven in rounds 1/4/5)
    int* wsi = (int*)d_ws;
    int*    offc  = wsi;                        // NCI ints   [0 .. 884736 B)
    int*    bsum  = wsi + NCI;                  // 1024 ints  [.. 888832 B)
    float*  parts = (float*)(wsi + NCI + 1024); // 288 floats [.. 889984 B)
    float4* pts   = (float4*)(wsi + NCI + 1312);// N2 float4  [.. 5608576 B), 16B-aligned

    zero_kernel<<<SCAN_BLOCKS, 256, 0, stream>>>(offc);
    count_kernel<<<N2 / 256, 256, 0, stream>>>(fake, tar, sh_p, sw_p, offc);
    scan1_kernel<<<SCAN_BLOCKS, 256, 0, stream>>>(offc, bsum);
    scan2_kernel<<<1, 1024, 0, stream>>>(bsum);
    scan3_kernel<<<SCAN_BLOCKS, 256, 0, stream>>>(offc, bsum);
    fill_kernel<<<N2 / 256, 256, 0, stream>>>(fake, tar, sh_p, sw_p, offc, pts);
    query_kernel<<<N2 / 256, 256, 0, stream>>>(pts, offc);
    reduce1<<<N2 / 1024, 256, 0, stream>>>(pts, parts);
    reduce2<<<1, 256, 0, stream>>>(parts, out);
}

// Round 8
// 670.125 us; speedup vs baseline: 7.0819x; 2.9786x over previous
//
#include <hip/hip_runtime.h>
#include <math.h>

// ChamferLoss on MI355X — round 8: grid NN with WAVE-PER-QUERY scanning.
// Round 7 (thread-per-query) measured 1780 µs: latency-bound (VALUBusy 20%,
// occupancy 8.6%) with the tail set by near-origin dense cells (~30K
// candidates scanned serially per lane). This round: one wave per query —
// 64 lanes stride the candidate rows, wave-uniform shell enumeration,
// shfl-reduced termination. Dense-query iteration count drops 64x.
// Pipeline (bin/scan/fill) and all math unchanged from the PASSING round 7.

#define N_PTS 147456          // 384*384
#define N2    (2 * N_PTS)     // both clouds
#define IMG_W 384
#define G     48              // grid edge
#define NC    (G * G * G)     // 110592 cells per cloud
#define NCI   (2 * NC)        // 221184 cells total
#define SCALE 0.48f           // cells per meter: (x+50)*SCALE in [0,48)
#define HC    2.0833333f      // cell width lower bound (conservative)
#define SCAN_BLOCKS 864       // NCI / 256

// ---- shared geometry (count & fill & query must agree exactly) ----

__device__ __forceinline__ float4 transform_pt(
    int idx, const float* __restrict__ fake, const float* __restrict__ tar,
    int sh, int sw)
{
    int pix = (idx < N_PTS) ? idx : idx - N_PTS;
    int r = pix / IMG_W, c = pix - r * IMG_W;
    float cw = (float)((double)sw / 1285.0 * 360.0);
    float ch = (float)((double)sh / 438.0 * 123.5);
    const float fh = (float)(360.0 * 384.0 / 1285.0);   // fh_crop
    const float fv = (float)(123.5 * 384.0 / 438.0);    // fv_crop
    const float D2R = 0.017453292519943295f;
    float yaw = ((-fh * (float)c) / 384.0f + cw) * D2R;
    float pit = ((-fv * (float)r) / 384.0f + ch) * D2R;
    float sy = sinf(yaw), cy = cosf(yaw);
    float sp = sinf(pit), cp = cosf(pit);
    float d = (idx < N_PTS) ? tar[pix] : fake[pix];   // A=transform(tar), B=transform(fake)
    return make_float4(d * sy * sp, d * cy * sp, d * cp, 0.f);
}

__device__ __forceinline__ int cell_coord(float v) {
    int c = (int)((v + 50.0f) * SCALE);
    return min(max(c, 0), G - 1);
}

__device__ __forceinline__ int cell_of(float x, float y, float z) {
    return (cell_coord(z) * G + cell_coord(y)) * G + cell_coord(x);
}

// ---- pipeline ----

__global__ __launch_bounds__(256) void zero_kernel(int* __restrict__ p) {
    p[blockIdx.x * 256 + threadIdx.x] = 0;   // grid = SCAN_BLOCKS covers NCI
}

__global__ __launch_bounds__(256) void count_kernel(
    const float* __restrict__ fake, const float* __restrict__ tar,
    const int* __restrict__ sh_p, const int* __restrict__ sw_p,
    int* __restrict__ offc)
{
    int idx = blockIdx.x * 256 + threadIdx.x;    // grid = N2/256
    float4 p = transform_pt(idx, fake, tar, *sh_p, *sw_p);
    int bucket = ((idx < N_PTS) ? 0 : NC) + cell_of(p.x, p.y, p.z);
    atomicAdd(&offc[bucket], 1);
}

__global__ __launch_bounds__(256) void scan1_kernel(
    int* __restrict__ offc, int* __restrict__ bsum)
{
    __shared__ int sd[256];
    int t = threadIdx.x;
    int gid = blockIdx.x * 256 + t;
    int c = offc[gid];
    sd[t] = c;
    __syncthreads();
    for (int o = 1; o < 256; o <<= 1) {
        int v = (t >= o) ? sd[t - o] : 0;
        __syncthreads();
        sd[t] += v;
        __syncthreads();
    }
    offc[gid] = sd[t] - c;                        // exclusive within block
    if (t == 255) bsum[blockIdx.x] = sd[255];
}

__global__ __launch_bounds__(1024) void scan2_kernel(int* __restrict__ bsum)
{
    __shared__ int sd[1024];
    int t = threadIdx.x;
    int v0 = (t < SCAN_BLOCKS) ? bsum[t] : 0;
    sd[t] = v0;
    __syncthreads();
    for (int o = 1; o < 1024; o <<= 1) {
        int v = (t >= o) ? sd[t - o] : 0;
        __syncthreads();
        sd[t] += v;
        __syncthreads();
    }
    if (t < SCAN_BLOCKS) bsum[t] = sd[t] - v0;    // exclusive
}

__global__ __launch_bounds__(256) void scan3_kernel(
    int* __restrict__ offc, const int* __restrict__ bsum)
{
    int gid = blockIdx.x * 256 + threadIdx.x;
    offc[gid] += bsum[blockIdx.x];
}

// scatter points into CSR slots; afterwards offc[c] = END offset of cell c
__global__ __launch_bounds__(256) void fill_kernel(
    const float* __restrict__ fake, const float* __restrict__ tar,
    const int* __restrict__ sh_p, const int* __restrict__ sw_p,
    int* __restrict__ offc, float4* __restrict__ pts)
{
    int idx = blockIdx.x * 256 + threadIdx.x;
    float4 p = transform_pt(idx, fake, tar, *sh_p, *sw_p);
    int bucket = ((idx < N_PTS) ? 0 : NC) + cell_of(p.x, p.y, p.z);
    int slot = atomicAdd(&offc[bucket], 1);
    pts[slot] = make_float4(p.x, p.y, p.z, 0.f);
}

// WAVE-PER-QUERY expanding-shell exact NN.
// CSR range of cells [c0..c1]: [ c0 ? offc[c0-1] : 0 , offc[c1] ).
__global__ __launch_bounds__(256) void query_kernel(
    float4* __restrict__ pts, const int* __restrict__ offc)
{
    const int lane = threadIdx.x & 63;
    const int g = blockIdx.x * 4 + (threadIdx.x >> 6);   // query slot, one/wave
    float4 q = pts[g];                                    // broadcast load
    const float qx = q.x, qy = q.y, qz = q.z;
    const int base = (g < N_PTS) ? NC : 0;                // search the OTHER grid

    // wave-uniform cell coords -> SGPRs for scalar enumeration
    int cx = __builtin_amdgcn_readfirstlane(cell_coord(qx));
    int cy = __builtin_amdgcn_readfirstlane(cell_coord(qy));
    int cz = __builtin_amdgcn_readfirstlane(cell_coord(qz));
    float fx = (qx + 50.0f) * SCALE - (float)cx;
    float fy = (qy + 50.0f) * SCALE - (float)cy;
    float fz = (qz + 50.0f) * SCALE - (float)cz;
    float m = fminf(fminf(fminf(fx, 1.0f - fx), fminf(fy, 1.0f - fy)),
                    fminf(fz, 1.0f - fz));
    m = fmaxf(m, 0.0f);

    float best = __builtin_inff();

    for (int s = 0; s <= G; ++s) {
        int zlo = max(cz - s, 0), zhi = min(cz + s, G - 1);
        for (int iz = zlo; iz <= zhi; ++iz) {
            int adz = iz - cz; adz = (adz < 0) ? -adz : adz;
            int ylo = max(cy - s, 0), yhi = min(cy + s, G - 1);
            for (int iy = ylo; iy <= yhi; ++iy) {
                int ady = iy - cy; ady = (ady < 0) ? -ady : ady;
                int rowb = base + (iz * G + iy) * G;
                if (adz == s || ady == s) {        // full row of the shell
                    int c0 = rowb + max(cx - s, 0);
                    int c1 = rowb + min(cx + s, G - 1);
                    int lo = c0 ? offc[c0 - 1] : 0;
                    int hi = offc[c1];
                    for (int j = lo + lane; j < hi; j += 64) {
                        float4 t = pts[j];
                        float dx = t.x - qx, dy = t.y - qy, dz = t.z - qz;
                        float d = fmaf(dx, dx, fmaf(dy, dy, dz * dz));
                        best = fminf(best, d);
                    }
                } else {                            // interior row: two end cells
                    if (cx - s >= 0) {
                        int c0 = rowb + cx - s;
                        int lo = c0 ? offc[c0 - 1] : 0;
                        int hi = offc[c0];
                        for (int j = lo + lane; j < hi; j += 64) {
                            float4 t = pts[j];
                            float dx = t.x - qx, dy = t.y - qy, dz = t.z - qz;
                            float d = fmaf(dx, dx, fmaf(dy, dy, dz * dz));
                            best = fminf(best, d);
                        }
                    }
                    if (cx + s <= G - 1) {
                        int c0 = rowb + cx + s;
                        int lo = c0 ? offc[c0 - 1] : 0;
                        int hi = offc[c0];
                        for (int j = lo + lane; j < hi; j += 64) {
                            float4 t = pts[j];
                            float dx = t.x - qx, dy = t.y - qy, dz = t.z - qz;
                            float d = fmaf(dx, dx, fmaf(dy, dy, dz * dz));
                            best = fminf(best, d);
                        }
                    }
                }
            }
        }
        // wave-min; leaves every lane holding the global running min
        #pragma unroll
        for (int o = 32; o; o >>= 1) best = fminf(best, __shfl_xor(best, o, 64));
        // all unscanned points are >= (s + m) cell-widths away (conservative)
        float bnd = ((float)s + m) * HC;
        if (best <= bnd * bnd) break;   // uniform after reduce
    }

    if (lane == 0) pts[g].w = best;   // readers consume xyz only
}

// deterministic sum of pts[*].w
__global__ __launch_bounds__(256) void reduce1(
    const float4* __restrict__ pts, float* __restrict__ partials)
{
    int tid = threadIdx.x;
    int basei = blockIdx.x * 1024;
    float s = 0.f;
    #pragma unroll
    for (int t = 0; t < 4; t++) s += pts[basei + t * 256 + tid].w;
    #pragma unroll
    for (int o = 32; o; o >>= 1) s += __shfl_xor(s, o, 64);
    __shared__ float wsum[4];
    if ((tid & 63) == 0) wsum[tid >> 6] = s;
    __syncthreads();
    if (tid == 0) partials[blockIdx.x] = wsum[0] + wsum[1] + wsum[2] + wsum[3];
}

__global__ __launch_bounds__(256) void reduce2(
    const float* __restrict__ partials, float* __restrict__ out)
{
    int tid = threadIdx.x;
    float s = 0.f;
    for (int i = tid; i < 288; i += 256) s += partials[i];
    #pragma unroll
    for (int o = 32; o; o >>= 1) s += __shfl_xor(s, o, 64);
    __shared__ float wsum[4];
    if ((tid & 63) == 0) wsum[tid >> 6] = s;
    __syncthreads();
    if (tid == 0) out[0] = (wsum[0] + wsum[1] + wsum[2] + wsum[3]) / 147456.0f;
}

extern "C" void kernel_launch(void* const* d_in, const int* in_sizes, int n_in,
                              void* d_out, int out_size, void* d_ws, size_t ws_size,
                              hipStream_t stream) {
    const float* fake = (const float*)d_in[0];
    const float* tar  = (const float*)d_in[1];
    const int*   sh_p = (const int*)d_in[2];
    const int*   sw_p = (const int*)d_in[3];
    float* out = (float*)d_out;

    // ws layout: total 5,608,576 B = 5.35 MB (< 5.90 MB proven in rounds 1/4/5)
    int* wsi = (int*)d_ws;
    int*    offc  = wsi;                        // NCI ints
    int*    bsum  = wsi + NCI;                  // 1024 ints
    float*  parts = (float*)(wsi + NCI + 1024); // 288 floats
    float4* pts   = (float4*)(wsi + NCI + 1312);// N2 float4, 16B-aligned

    zero_kernel<<<SCAN_BLOCKS, 256, 0, stream>>>(offc);
    count_kernel<<<N2 / 256, 256, 0, stream>>>(fake, tar, sh_p, sw_p, offc);
    scan1_kernel<<<SCAN_BLOCKS, 256, 0, stream>>>(offc, bsum);
    scan2_kernel<<<1, 1024, 0, stream>>>(bsum);
    scan3_kernel<<<SCAN_BLOCKS, 256, 0, stream>>>(offc, bsum);
    fill_kernel<<<N2 / 256, 256, 0, stream>>>(fake, tar, sh_p, sw_p, offc, pts);
    query_kernel<<<N2 / 4, 256, 0, stream>>>(pts, offc);   // one wave per query
    reduce1<<<N2 / 1024, 256, 0, stream>>>(pts, parts);
    reduce2<<<1, 256, 0, stream>>>(parts, out);
}